// Round 16
// baseline (63.414 us; speedup 1.0000x reference)
//
#include <hip/hip_runtime.h>
#include <hip/hip_bf16.h>
#include <stdint.h>

typedef __bf16 bf16_t;
typedef __bf16 bf16x8 __attribute__((ext_vector_type(8)));
typedef float  f32x4  __attribute__((ext_vector_type(4)));
typedef float  f32x16 __attribute__((ext_vector_type(16)));
typedef unsigned int uint;
typedef uint uintx4 __attribute__((ext_vector_type(4)));

#define MFMA16(a,b,c) __builtin_amdgcn_mfma_f32_16x16x32_bf16((a),(b),(c),0,0,0)
#define MFMA32(a,b,c) __builtin_amdgcn_mfma_f32_32x32x16_bf16((a),(b),(c),0,0,0)

constexpr int NB = 16;
constexpr int LQ = 8192;
constexpr int LK = 128;
constexpr int H  = 128;

// log2(e) / sqrt(H): fold softmax scale + exp2 conversion into one multiply
constexpr float C1 = 1.4426950408889634f / 11.313708498984761f;

constexpr size_t WS_MV = 1024;                              // 16 x 64KB M/V images
constexpr size_t WS_BM = WS_MV + (size_t)NB * 65536;        // bitmask: 16B per q-row (2 MB)

// XOR swizzle for [*][128] bf16 LDS tiles (row stride 256 B)
__device__ __forceinline__ unsigned swz(unsigned row, unsigned byte) {
  return row * 256u + (byte ^ ((row & 15u) << 4));
}

__device__ __forceinline__ bf16x8 cvt_frag(const float* p) {
  f32x4 u0 = *(const f32x4*)p;
  f32x4 u1 = *(const f32x4*)(p + 4);
  bf16x8 v;
  #pragma unroll
  for (int e = 0; e < 4; ++e) { v[e] = (bf16_t)u0[e]; v[e + 4] = (bf16_t)u1[e]; }
  return v;
}

__device__ __forceinline__ f32x16 zero16() {
  f32x16 z;
  #pragma unroll
  for (int i = 0; i < 16; ++i) z[i] = 0.f;
  return z;
}

// v_cvt_pk_bf16_f32: lo = bf16(a), hi = bf16(b)
__device__ __forceinline__ uint pkbf(float a, float b) {
  uint d;
  asm("v_cvt_pk_bf16_f32 %0, %1, %2" : "=v"(d) : "v"(a), "v"(b));
  return d;
}

// async global->LDS, 16 bytes per lane
__device__ __forceinline__ void gl16(const void* g, void* l) {
  __builtin_amdgcn_global_load_lds(
      (const __attribute__((address_space(1))) uint32_t*)g,
      (__attribute__((address_space(3))) uint32_t*)l, 16, 0, 0);
}

// ---------------------------------------------------------------------------
// prep (544 blocks):
//   blocks 0..31: M_b / V_b build (r8-r15 validated code, swizzled image to ws)
//   blocks 32..543: mask -> bitmask pack (16 B per q-row; 256 rows per block).
//   Pack blocks self-detect the mask dtype (r1-validated heuristic) and run
//   concurrently with the latency-bound build blocks on the idle CUs.
// ---------------------------------------------------------------------------
__global__ __launch_bounds__(512) void prep_kernel(
    const float* __restrict__ x2, const float* __restrict__ wq,
    const float* __restrict__ wk, const float* __restrict__ wv,
    const void* __restrict__ x3, uint8_t* __restrict__ ws)
{
  __shared__ uint8_t sP[131072];  // [wqT 32K | wkT 32K | W2T lin 32K | out 32K]
  __shared__ int sF32, sBig;
  const int tid = threadIdx.x;
  const int l = tid & 63, w = tid >> 6, q31 = l & 31, hi2 = l >> 5;

  if (blockIdx.x >= 32) {
    // ---- bitmask pack block: rows [pb*256, pb*256+256) ----
    const int pb = blockIdx.x - 32;
    // mask dtype probe over first 2048 words of x3 (r1 heuristic):
    // int32 bool -> words in {0,1}; uint8 bool -> words like 0x01010101 (>1);
    // f32 bool -> words in {0, 0x3f800000}
    if (tid == 0) { sF32 = 0; sBig = 0; }
    __syncthreads();
    {
      const uint* x3w = (const uint*)x3;
      int f = 0, g = 0;
      #pragma unroll
      for (int j = 0; j < 4; ++j) {
        uint v = x3w[tid * 4 + j];
        if (v == 0x3f800000u) f = 1;
        else if (v > 1u) g = 1;
      }
      if (f) sF32 = 1;
      if (g) sBig = 1;
    }
    __syncthreads();
    const int byteMode = (sF32 == 0 && sBig == 1) ? 1 : 0;

    // wave w packs rows pb*256 + w*32 + rr, rr = 0..31
    uint8_t* bm = ws + WS_BM;
    #pragma unroll 4
    for (int rr = 0; rr < 32; ++rr) {
      const size_t row = (size_t)pb * 256 + w * 32 + rr;
      unsigned long long b0, b1;
      if (byteMode) {
        const uint8_t* rp = (const uint8_t*)x3 + row * 128;
        b0 = __ballot(rp[l] != 0);
        b1 = __ballot(rp[64 + l] != 0);
      } else {
        const uint* rp = (const uint*)x3 + row * 128;
        b0 = __ballot(rp[l] != 0);
        b1 = __ballot(rp[64 + l] != 0);
      }
      if (l == 0) {
        *(unsigned long long*)(bm + row * 16)     = b0;
        *(unsigned long long*)(bm + row * 16 + 8) = b1;
      }
    }
    return;
  }

  // ---- build blocks (unchanged, validated) ----
  const int b = blockIdx.x >> 1, which = blockIdx.x & 1;
  uint8_t* sOut = sP + 98304;

  if (which == 0) {
    // stage wqT / wkT swizzled
    {
      const int row = tid >> 2, c0 = (tid & 3) * 32;
      #pragma unroll
      for (int wh = 0; wh < 2; ++wh) {
        const float* W = wh ? wk : wq;
        uint8_t* dst = sP + wh * 32768;
        const float* s = W + row * H + c0;
        #pragma unroll
        for (int j = 0; j < 32; ++j)
          *(bf16_t*)(dst + swz(c0 + j, row * 2)) = (bf16_t)s[j];
      }
    }
    __syncthreads();

    // W2T[i][j] = sum_k wq[k][i] wk[k][j]  -> LDS linear [128][128] bf16
    {
      const int lo = l & 15, hi = l >> 4;
      bf16x8 a4[4];
      #pragma unroll
      for (int kk = 0; kk < 4; ++kk)
        a4[kk] = *(const bf16x8*)(sP + swz(16 * w + lo, kk * 64 + hi * 16));
      bf16_t* W2T = (bf16_t*)(sP + 65536);
      #pragma unroll
      for (int t = 0; t < 8; ++t) {
        f32x4 c = {0.f, 0.f, 0.f, 0.f};
        #pragma unroll
        for (int kk = 0; kk < 4; ++kk)
          c = MFMA16(a4[kk], *(const bf16x8*)(sP + 32768 + swz(16 * t + lo, kk * 64 + hi * 16)), c);
        #pragma unroll
        for (int r = 0; r < 4; ++r)
          W2T[(16 * w + hi * 4 + r) * H + 16 * t + lo] = (bf16_t)c[r];
      }
    }
    __syncthreads();

    // M build
    if (w < 4) {
      const int wb = w;
      bf16x8 axf[8];
      const float* x2r = x2 + ((size_t)b * LK + 32 * wb + q31) * H;
      #pragma unroll
      for (int kt = 0; kt < 8; ++kt)
        axf[kt] = cvt_frag(x2r + kt * 16 + 8 * hi2);
      const bf16_t* W2Tl = (const bf16_t*)(sP + 65536);
      #pragma unroll
      for (int nt = 0; nt < 4; ++nt) {
        f32x16 c = zero16();
        #pragma unroll
        for (int kt = 0; kt < 8; ++kt)
          c = MFMA32(axf[kt],
                     *(const bf16x8*)(W2Tl + (size_t)(nt * 32 + q31) * H + kt * 16 + 8 * hi2), c);
        #pragma unroll
        for (int r = 0; r < 16; ++r)
          *(bf16_t*)(sOut + swz(32 * wb + (r & 3) + 8 * (r >> 2) + 4 * hi2,
                                (nt * 32 + q31) * 2)) = (bf16_t)c[r];
      }
    }
  } else {
    // V build
    if (w < 4) {
      const int wb = w;
      bf16x8 axf[8];
      const float* x2r = x2 + ((size_t)b * LK + 32 * wb + q31) * H;
      #pragma unroll
      for (int kt = 0; kt < 8; ++kt)
        axf[kt] = cvt_frag(x2r + kt * 16 + 8 * hi2);
      #pragma unroll
      for (int nt = 0; nt < 4; ++nt) {
        f32x16 c = zero16();
        #pragma unroll
        for (int kt = 0; kt < 8; ++kt)
          c = MFMA32(axf[kt],
                     cvt_frag(wv + (size_t)(nt * 32 + q31) * H + kt * 16 + 8 * hi2), c);
        #pragma unroll
        for (int r = 0; r < 16; ++r)
          *(bf16_t*)(sOut + swz(32 * wb + (r & 3) + 8 * (r >> 2) + 4 * hi2,
                                (nt * 32 + q31) * 2)) = (bf16_t)c[r];
      }
    }
  }
  __syncthreads();

  // copy the 32 KB swizzled image to ws (linear)
  {
    const uint4* src = (const uint4*)sOut;
    uint4* dst = (uint4*)(ws + WS_MV + (size_t)b * 65536 + (size_t)which * 32768);
    #pragma unroll
    for (int j = 0; j < 4; ++j)
      dst[tid + j * 512] = src[tid + j * 512];
  }
}

// ---- pass macros (straight-line, register-resident; rule #20: no dyn idx) ----

// S + softmax + pb from raw xr regs and bitmask word-vector MB (uintx4)
#define CONV_S_PB(XR, MB)                                                      \
  {                                                                            \
    bf16x8 xbf[8];                                                             \
    _Pragma("unroll")                                                          \
    for (int kt = 0; kt < 8; ++kt) {                                           \
      _Pragma("unroll")                                                        \
      for (int e = 0; e < 4; ++e) {                                            \
        xbf[kt][e]     = (bf16_t)XR[2 * kt][e];                                \
        xbf[kt][e + 4] = (bf16_t)XR[2 * kt + 1][e];                            \
      }                                                                        \
    }                                                                          \
    _Pragma("unroll")                                                          \
    for (int half = 0; half < 2; ++half) {                                     \
      const int jt0 = half * 2, jt1 = half * 2 + 1;                            \
      f32x16 s0 = zero16(), s1 = zero16();                                     \
      __builtin_amdgcn_s_setprio(1);                                           \
      _Pragma("unroll")                                                        \
      for (int kt = 0; kt < 8; ++kt) {                                         \
        s0 = MFMA32(*(const bf16x8*)(sM + swz(jt0 * 32 + q31, kt * 32 + hi2 * 16)), \
                    xbf[kt], s0);                                              \
        s1 = MFMA32(*(const bf16x8*)(sM + swz(jt1 * 32 + q31, kt * 32 + hi2 * 16)), \
                    xbf[kt], s1);                                              \
      }                                                                        \
      __builtin_amdgcn_s_setprio(0);                                           \
      _Pragma("unroll")                                                        \
      for (int jj = 0; jj < 2; ++jj) {                                         \
        f32x16& sj = jj ? s1 : s0;                                             \
        const int jt = half * 2 + jj;                                          \
        _Pragma("unroll")                                                      \
        for (int rg = 0; rg < 4; ++rg) {                                       \
          const uint mw = MB[jt] >> (8 * rg + 4 * hi2);                        \
          float p0 = __builtin_amdgcn_exp2f(sj[rg * 4 + 0] * C1);              \
          float p1 = __builtin_amdgcn_exp2f(sj[rg * 4 + 1] * C1);              \
          float p2 = __builtin_amdgcn_exp2f(sj[rg * 4 + 2] * C1);              \
          float p3 = __builtin_amdgcn_exp2f(sj[rg * 4 + 3] * C1);              \
          sj[rg * 4 + 0] = (mw & 1u) ? 0.f : p0;                               \
          sj[rg * 4 + 1] = (mw & 2u) ? 0.f : p1;                               \
          sj[rg * 4 + 2] = (mw & 4u) ? 0.f : p2;                               \
          sj[rg * 4 + 3] = (mw & 8u) ? 0.f : p3;                               \
        }                                                                      \
        _Pragma("unroll")                                                      \
        for (int h = 0; h < 2; ++h) {                                          \
          uint A = pkbf(sj[h * 8 + 0], sj[h * 8 + 1]);                         \
          uint C = pkbf(sj[h * 8 + 2], sj[h * 8 + 3]);                         \
          uint B = pkbf(sj[h * 8 + 4], sj[h * 8 + 5]);                         \
          uint D = pkbf(sj[h * 8 + 6], sj[h * 8 + 7]);                         \
          asm("v_permlane32_swap_b32 %0, %1" : "+v"(A), "+v"(B));              \
          asm("v_permlane32_swap_b32 %0, %1" : "+v"(C), "+v"(D));              \
          uintx4 t2; t2.x = A; t2.y = C; t2.z = B; t2.w = D;                   \
          pb[jt * 2 + h] = __builtin_bit_cast(bf16x8, t2);                     \
        }                                                                      \
      }                                                                        \
    }                                                                          \
  }

// dsum + O tiles + non-temporal stores for pass at q column Q0W
#define O_STORE(Q0W)                                                           \
  {                                                                            \
    f32x16 dacc = zero16();                                                    \
    {                                                                          \
      f32x16 o0 = zero16(), o1 = zero16();                                     \
      __builtin_amdgcn_s_setprio(1);                                           \
      _Pragma("unroll")                                                        \
      for (int kt = 0; kt < 8; ++kt) {                                         \
        dacc = MFMA32(ones1, pb[kt], dacc);                                    \
        o0 = MFMA32(*(const bf16x8*)(sV + swz(0 * 32 + q31, kt * 32 + hi2 * 16)), pb[kt], o0); \
        o1 = MFMA32(*(const bf16x8*)(sV + swz(1 * 32 + q31, kt * 32 + hi2 * 16)), pb[kt], o1); \
      }                                                                        \
      __builtin_amdgcn_s_setprio(0);                                           \
      const float inv = 1.0f / dacc[0];                                        \
      _Pragma("unroll")                                                        \
      for (int r = 0; r < 16; ++r) {                                           \
        const int ibase = (r & 3) + 8 * (r >> 2) + 4 * hi2;                    \
        __builtin_nontemporal_store(o0[r] * inv,                               \
            &out[((size_t)b * LK + ibase) * LQ + (Q0W) + q31]);                \
        __builtin_nontemporal_store(o1[r] * inv,                               \
            &out[((size_t)b * LK + 32 + ibase) * LQ + (Q0W) + q31]);           \
      }                                                                        \
      f32x16 o2 = zero16(), o3 = zero16();                                     \
      __builtin_amdgcn_s_setprio(1);                                           \
      _Pragma("unroll")                                                        \
      for (int kt = 0; kt < 8; ++kt) {                                         \
        o2 = MFMA32(*(const bf16x8*)(sV + swz(2 * 32 + q31, kt * 32 + hi2 * 16)), pb[kt], o2); \
        o3 = MFMA32(*(const bf16x8*)(sV + swz(3 * 32 + q31, kt * 32 + hi2 * 16)), pb[kt], o3); \
      }                                                                        \
      __builtin_amdgcn_s_setprio(0);                                           \
      _Pragma("unroll")                                                        \
      for (int r = 0; r < 16; ++r) {                                           \
        const int ibase = (r & 3) + 8 * (r >> 2) + 4 * hi2;                    \
        __builtin_nontemporal_store(o2[r] * inv,                               \
            &out[((size_t)b * LK + 64 + ibase) * LQ + (Q0W) + q31]);           \
        __builtin_nontemporal_store(o3[r] * inv,                               \
            &out[((size_t)b * LK + 96 + ibase) * LQ + (Q0W) + q31]);           \
      }                                                                        \
    }                                                                          \
  }

// ---------------------------------------------------------------------------
// Main fused kernel — r15 structure with bitmask (1 dense uint4 per row per
// pass instead of 16 scattered dword loads; x3 no longer touched).
// Block = 256 threads (4 waves x 2 subtiles of 32 rows); grid 512 with the
// bijective batch->XCD swizzle; NT stores; pass-1 loads overlap pass-0
// stores. LDS 64 KB -> 2 blocks/CU.
// ---------------------------------------------------------------------------
__global__ __launch_bounds__(256, 2) void attn_kernel(
    const float* __restrict__ x1, const uint8_t* __restrict__ ws,
    float* __restrict__ out)
{
  __shared__ uint8_t sm[65536];
  uint8_t* sM = sm;            // M [128 j][128 c] bf16 swizzled
  uint8_t* sV = sm + 32768;    // V [128 i][128 j] bf16 swizzled

  const int tid = threadIdx.x, blk = blockIdx.x;
  const int xcd = blk & 7;          // hw XCD (round-robin dispatch)
  const int t   = blk >> 3;         // 0..63
  const int b   = ((t & 1) << 3) | xcd;
  const int qc  = (t >> 1) * 256;
  const int l = tid & 63, w4 = tid >> 6;
  const int q31 = l & 31, hi2 = l >> 5;

  const int q0w0 = qc + w4 * 64;        // pass-0 columns
  const int q0w1 = q0w0 + 32;           // pass-1 columns
  const size_t qrow0 = (size_t)b * LQ + q0w0 + q31;
  const size_t qrow1 = qrow0 + 32;

  const uint8_t* bm = ws + WS_BM;

  // ---- M/V image: async global->LDS (64 KB; 16 gl16 per thread) ----
  {
    const uint8_t* g = ws + WS_MV + (size_t)b * 65536;
    #pragma unroll
    for (int j = 0; j < 16; ++j)
      gl16(g + tid * 16 + j * 4096, sm + tid * 16 + j * 4096);
  }

  // ---- pass-0 x1 + bitmask loads ----
  f32x4 xr0[16];
  uintx4 mb0;
  {
    const float* xp = x1 + qrow0 * H;
    #pragma unroll
    for (int kt = 0; kt < 8; ++kt) {
      xr0[2 * kt]     = *(const f32x4*)(xp + kt * 16 + 8 * hi2);
      xr0[2 * kt + 1] = *(const f32x4*)(xp + kt * 16 + 8 * hi2 + 4);
    }
    mb0 = *(const uintx4*)(bm + qrow0 * 16);
  }
  __syncthreads();   // drains gl16 image + pass-0 loads

  bf16x8 ones1;
  #pragma unroll
  for (int e = 0; e < 8; ++e) ones1[e] = (bf16_t)1.f;

  bf16x8 pb[8];

  // ---- pass 0: S + softmax + pb ----
  CONV_S_PB(xr0, mb0)

  // ---- issue pass-1 loads (overlap with pass-0 O/store phase) ----
  f32x4 xr1[16];
  uintx4 mb1;
  {
    const float* xp = x1 + qrow1 * H;
    #pragma unroll
    for (int kt = 0; kt < 8; ++kt) {
      xr1[2 * kt]     = *(const f32x4*)(xp + kt * 16 + 8 * hi2);
      xr1[2 * kt + 1] = *(const f32x4*)(xp + kt * 16 + 8 * hi2 + 4);
    }
    mb1 = *(const uintx4*)(bm + qrow1 * 16);
  }

  // ---- pass 0: O + NT stores (pass-1 loads in flight) ----
  O_STORE(q0w0)

  // ---- pass 1 ----
  CONV_S_PB(xr1, mb1)
  O_STORE(q0w1)
}

extern "C" void kernel_launch(void* const* d_in, const int* in_sizes, int n_in,
                              void* d_out, int out_size, void* d_ws, size_t ws_size,
                              hipStream_t stream) {
  const float* x1 = (const float*)d_in[0];
  const float* x2 = (const float*)d_in[1];
  const void*  x3 = d_in[2];
  const float* wq = (const float*)d_in[3];
  const float* wk = (const float*)d_in[4];
  const float* wv = (const float*)d_in[5];
  uint8_t* ws = (uint8_t*)d_ws;
  float* out = (float*)d_out;

  prep_kernel<<<32 + 512, 512, 0, stream>>>(x2, wq, wk, wv, x3, ws);
  attn_kernel<<<NB * (LQ / 256), 256, 0, stream>>>(x1, ws, out);
}

// Round 17
// 62.421 us; speedup vs baseline: 1.0159x; 1.0159x over previous
//
#include <hip/hip_runtime.h>
#include <hip/hip_bf16.h>
#include <stdint.h>

typedef __bf16 bf16_t;
typedef __bf16 bf16x8 __attribute__((ext_vector_type(8)));
typedef float  f32x4  __attribute__((ext_vector_type(4)));
typedef float  f32x16 __attribute__((ext_vector_type(16)));
typedef unsigned int uint;
typedef unsigned short ushort_t;
typedef uint uintx4 __attribute__((ext_vector_type(4)));

#define MFMA16(a,b,c) __builtin_amdgcn_mfma_f32_16x16x32_bf16((a),(b),(c),0,0,0)
#define MFMA32(a,b,c) __builtin_amdgcn_mfma_f32_32x32x16_bf16((a),(b),(c),0,0,0)

constexpr int NB = 16;
constexpr int LQ = 8192;
constexpr int LK = 128;
constexpr int H  = 128;

// log2(e) / sqrt(H): fold softmax scale + exp2 conversion into one multiply
constexpr float C1 = 1.4426950408889634f / 11.313708498984761f;

constexpr size_t WS_MV = 1024;                              // 16 x 64KB M/V images
constexpr size_t WS_BM = WS_MV + (size_t)NB * 65536;        // bitmask: 16B per q-row (2 MB)

// XOR swizzle for [*][128] bf16 LDS tiles (row stride 256 B)
__device__ __forceinline__ unsigned swz(unsigned row, unsigned byte) {
  return row * 256u + (byte ^ ((row & 15u) << 4));
}

__device__ __forceinline__ bf16x8 cvt_frag(const float* p) {
  f32x4 u0 = *(const f32x4*)p;
  f32x4 u1 = *(const f32x4*)(p + 4);
  bf16x8 v;
  #pragma unroll
  for (int e = 0; e < 4; ++e) { v[e] = (bf16_t)u0[e]; v[e + 4] = (bf16_t)u1[e]; }
  return v;
}

__device__ __forceinline__ f32x16 zero16() {
  f32x16 z;
  #pragma unroll
  for (int i = 0; i < 16; ++i) z[i] = 0.f;
  return z;
}

// v_cvt_pk_bf16_f32: lo = bf16(a), hi = bf16(b)
__device__ __forceinline__ uint pkbf(float a, float b) {
  uint d;
  asm("v_cvt_pk_bf16_f32 %0, %1, %2" : "=v"(d) : "v"(a), "v"(b));
  return d;
}

// async global->LDS, 16 bytes per lane
__device__ __forceinline__ void gl16(const void* g, void* l) {
  __builtin_amdgcn_global_load_lds(
      (const __attribute__((address_space(1))) uint32_t*)g,
      (__attribute__((address_space(3))) uint32_t*)l, 16, 0, 0);
}

// ---------------------------------------------------------------------------
// prep (544 blocks):
//   blocks 0..31: M_b / V_b build (r8-r16 validated code, swizzled image to ws)
//   blocks 32..543: mask -> bitmask pack, DENSE uintx4 loads (1 KB/wave-instr)
//   + in-register byte->bit reduction (fixes r16's 64 B/instr ballot pack).
// ---------------------------------------------------------------------------
__global__ __launch_bounds__(512) void prep_kernel(
    const float* __restrict__ x2, const float* __restrict__ wq,
    const float* __restrict__ wk, const float* __restrict__ wv,
    const void* __restrict__ x3, uint8_t* __restrict__ ws)
{
  __shared__ uint8_t sP[131072];  // [wqT 32K | wkT 32K | W2T lin 32K | out 32K]
  __shared__ int sF32, sBig;
  const int tid = threadIdx.x;
  const int l = tid & 63, w = tid >> 6, q31 = l & 31, hi2 = l >> 5;

  if (blockIdx.x >= 32) {
    // ---- bitmask pack block: rows [pb*256, pb*256+256) ----
    const int pb = blockIdx.x - 32;
    // mask dtype probe over first 2048 words of x3 (r1 heuristic):
    // int32 bool -> words in {0,1}; uint8 bool -> words like 0x01010101 (>1);
    // f32 bool -> words in {0, 0x3f800000}
    if (tid == 0) { sF32 = 0; sBig = 0; }
    __syncthreads();
    {
      const uint* x3w = (const uint*)x3;
      int f = 0, g = 0;
      #pragma unroll
      for (int j = 0; j < 4; ++j) {
        uint v = x3w[tid * 4 + j];
        if (v == 0x3f800000u) f = 1;
        else if (v > 1u) g = 1;
      }
      if (f) sF32 = 1;
      if (g) sBig = 1;
    }
    __syncthreads();
    const int byteMode = (sF32 == 0 && sBig == 1) ? 1 : 0;

    uint8_t* bm = ws + WS_BM;
    if (byteMode) {
      // dense path: each idx handles 16 consecutive mask bytes -> 16 bits
      const uint8_t* src = (const uint8_t*)x3 + (size_t)pb * 256 * 128;
      #pragma unroll
      for (int rd = 0; rd < 4; ++rd) {
        const int idx = tid + rd * 512;               // 0..2047
        uintx4 v = *(const uintx4*)(src + (size_t)idx * 16);
        uint bits = 0;
        #pragma unroll
        for (int j = 0; j < 4; ++j) {
          const uint word = v[j];
          bits |= ((word & 0x000000ffu) ? 1u : 0u) << (4 * j + 0);
          bits |= ((word & 0x0000ff00u) ? 1u : 0u) << (4 * j + 1);
          bits |= ((word & 0x00ff0000u) ? 1u : 0u) << (4 * j + 2);
          bits |= ((word & 0xff000000u) ? 1u : 0u) << (4 * j + 3);
        }
        const size_t row = (size_t)pb * 256 + (idx >> 3);
        *(ushort_t*)(bm + row * 16 + (size_t)(idx & 7) * 2) = (ushort_t)bits;
      }
    } else {
      // word-mode fallback (ballot; mask probe says byteMode in practice)
      #pragma unroll 4
      for (int rr = 0; rr < 32; ++rr) {
        const size_t row = (size_t)pb * 256 + w * 32 + rr;
        const uint* rp = (const uint*)x3 + row * 128;
        unsigned long long b0 = __ballot(rp[l] != 0);
        unsigned long long b1 = __ballot(rp[64 + l] != 0);
        if (l == 0) {
          *(unsigned long long*)(bm + row * 16)     = b0;
          *(unsigned long long*)(bm + row * 16 + 8) = b1;
        }
      }
    }
    return;
  }

  // ---- build blocks (unchanged, validated) ----
  const int b = blockIdx.x >> 1, which = blockIdx.x & 1;
  uint8_t* sOut = sP + 98304;

  if (which == 0) {
    // stage wqT / wkT swizzled
    {
      const int row = tid >> 2, c0 = (tid & 3) * 32;
      #pragma unroll
      for (int wh = 0; wh < 2; ++wh) {
        const float* W = wh ? wk : wq;
        uint8_t* dst = sP + wh * 32768;
        const float* s = W + row * H + c0;
        #pragma unroll
        for (int j = 0; j < 32; ++j)
          *(bf16_t*)(dst + swz(c0 + j, row * 2)) = (bf16_t)s[j];
      }
    }
    __syncthreads();

    // W2T[i][j] = sum_k wq[k][i] wk[k][j]  -> LDS linear [128][128] bf16
    {
      const int lo = l & 15, hi = l >> 4;
      bf16x8 a4[4];
      #pragma unroll
      for (int kk = 0; kk < 4; ++kk)
        a4[kk] = *(const bf16x8*)(sP + swz(16 * w + lo, kk * 64 + hi * 16));
      bf16_t* W2T = (bf16_t*)(sP + 65536);
      #pragma unroll
      for (int t = 0; t < 8; ++t) {
        f32x4 c = {0.f, 0.f, 0.f, 0.f};
        #pragma unroll
        for (int kk = 0; kk < 4; ++kk)
          c = MFMA16(a4[kk], *(const bf16x8*)(sP + 32768 + swz(16 * t + lo, kk * 64 + hi * 16)), c);
        #pragma unroll
        for (int r = 0; r < 4; ++r)
          W2T[(16 * w + hi * 4 + r) * H + 16 * t + lo] = (bf16_t)c[r];
      }
    }
    __syncthreads();

    // M build
    if (w < 4) {
      const int wb = w;
      bf16x8 axf[8];
      const float* x2r = x2 + ((size_t)b * LK + 32 * wb + q31) * H;
      #pragma unroll
      for (int kt = 0; kt < 8; ++kt)
        axf[kt] = cvt_frag(x2r + kt * 16 + 8 * hi2);
      const bf16_t* W2Tl = (const bf16_t*)(sP + 65536);
      #pragma unroll
      for (int nt = 0; nt < 4; ++nt) {
        f32x16 c = zero16();
        #pragma unroll
        for (int kt = 0; kt < 8; ++kt)
          c = MFMA32(axf[kt],
                     *(const bf16x8*)(W2Tl + (size_t)(nt * 32 + q31) * H + kt * 16 + 8 * hi2), c);
        #pragma unroll
        for (int r = 0; r < 16; ++r)
          *(bf16_t*)(sOut + swz(32 * wb + (r & 3) + 8 * (r >> 2) + 4 * hi2,
                                (nt * 32 + q31) * 2)) = (bf16_t)c[r];
      }
    }
  } else {
    // V build
    if (w < 4) {
      const int wb = w;
      bf16x8 axf[8];
      const float* x2r = x2 + ((size_t)b * LK + 32 * wb + q31) * H;
      #pragma unroll
      for (int kt = 0; kt < 8; ++kt)
        axf[kt] = cvt_frag(x2r + kt * 16 + 8 * hi2);
      #pragma unroll
      for (int nt = 0; nt < 4; ++nt) {
        f32x16 c = zero16();
        #pragma unroll
        for (int kt = 0; kt < 8; ++kt)
          c = MFMA32(axf[kt],
                     cvt_frag(wv + (size_t)(nt * 32 + q31) * H + kt * 16 + 8 * hi2), c);
        #pragma unroll
        for (int r = 0; r < 16; ++r)
          *(bf16_t*)(sOut + swz(32 * wb + (r & 3) + 8 * (r >> 2) + 4 * hi2,
                                (nt * 32 + q31) * 2)) = (bf16_t)c[r];
      }
    }
  }
  __syncthreads();

  // copy the 32 KB swizzled image to ws (linear)
  {
    const uint4* src = (const uint4*)sOut;
    uint4* dst = (uint4*)(ws + WS_MV + (size_t)b * 65536 + (size_t)which * 32768);
    #pragma unroll
    for (int j = 0; j < 4; ++j)
      dst[tid + j * 512] = src[tid + j * 512];
  }
}

// ---- pass macros (straight-line, register-resident; rule #20: no dyn idx) ----

// S + softmax + pb from raw xr regs and bitmask word-vector MB (uintx4)
#define CONV_S_PB(XR, MB)                                                      \
  {                                                                            \
    bf16x8 xbf[8];                                                             \
    _Pragma("unroll")                                                          \
    for (int kt = 0; kt < 8; ++kt) {                                           \
      _Pragma("unroll")                                                        \
      for (int e = 0; e < 4; ++e) {                                            \
        xbf[kt][e]     = (bf16_t)XR[2 * kt][e];                                \
        xbf[kt][e + 4] = (bf16_t)XR[2 * kt + 1][e];                            \
      }                                                                        \
    }                                                                          \
    _Pragma("unroll")                                                          \
    for (int half = 0; half < 2; ++half) {                                     \
      const int jt0 = half * 2, jt1 = half * 2 + 1;                            \
      f32x16 s0 = zero16(), s1 = zero16();                                     \
      __builtin_amdgcn_s_setprio(1);                                           \
      _Pragma("unroll")                                                        \
      for (int kt = 0; kt < 8; ++kt) {                                         \
        s0 = MFMA32(*(const bf16x8*)(sM + swz(jt0 * 32 + q31, kt * 32 + hi2 * 16)), \
                    xbf[kt], s0);                                              \
        s1 = MFMA32(*(const bf16x8*)(sM + swz(jt1 * 32 + q31, kt * 32 + hi2 * 16)), \
                    xbf[kt], s1);                                              \
      }                                                                        \
      __builtin_amdgcn_s_setprio(0);                                           \
      _Pragma("unroll")                                                        \
      for (int jj = 0; jj < 2; ++jj) {                                         \
        f32x16& sj = jj ? s1 : s0;                                             \
        const int jt = half * 2 + jj;                                          \
        _Pragma("unroll")                                                      \
        for (int rg = 0; rg < 4; ++rg) {                                       \
          const uint mw = MB[jt] >> (8 * rg + 4 * hi2);                        \
          float p0 = __builtin_amdgcn_exp2f(sj[rg * 4 + 0] * C1);              \
          float p1 = __builtin_amdgcn_exp2f(sj[rg * 4 + 1] * C1);              \
          float p2 = __builtin_amdgcn_exp2f(sj[rg * 4 + 2] * C1);              \
          float p3 = __builtin_amdgcn_exp2f(sj[rg * 4 + 3] * C1);              \
          sj[rg * 4 + 0] = (mw & 1u) ? 0.f : p0;                               \
          sj[rg * 4 + 1] = (mw & 2u) ? 0.f : p1;                               \
          sj[rg * 4 + 2] = (mw & 4u) ? 0.f : p2;                               \
          sj[rg * 4 + 3] = (mw & 8u) ? 0.f : p3;                               \
        }                                                                      \
        _Pragma("unroll")                                                      \
        for (int h = 0; h < 2; ++h) {                                          \
          uint A = pkbf(sj[h * 8 + 0], sj[h * 8 + 1]);                         \
          uint C = pkbf(sj[h * 8 + 2], sj[h * 8 + 3]);                         \
          uint B = pkbf(sj[h * 8 + 4], sj[h * 8 + 5]);                         \
          uint D = pkbf(sj[h * 8 + 6], sj[h * 8 + 7]);                         \
          asm("v_permlane32_swap_b32 %0, %1" : "+v"(A), "+v"(B));              \
          asm("v_permlane32_swap_b32 %0, %1" : "+v"(C), "+v"(D));              \
          uintx4 t2; t2.x = A; t2.y = C; t2.z = B; t2.w = D;                   \
          pb[jt * 2 + h] = __builtin_bit_cast(bf16x8, t2);                     \
        }                                                                      \
      }                                                                        \
    }                                                                          \
  }

// dsum + O tiles + non-temporal stores for pass at q column Q0W
#define O_STORE(Q0W)                                                           \
  {                                                                            \
    f32x16 dacc = zero16();                                                    \
    {                                                                          \
      f32x16 o0 = zero16(), o1 = zero16();                                     \
      __builtin_amdgcn_s_setprio(1);                                           \
      _Pragma("unroll")                                                        \
      for (int kt = 0; kt < 8; ++kt) {                                         \
        dacc = MFMA32(ones1, pb[kt], dacc);                                    \
        o0 = MFMA32(*(const bf16x8*)(sV + swz(0 * 32 + q31, kt * 32 + hi2 * 16)), pb[kt], o0); \
        o1 = MFMA32(*(const bf16x8*)(sV + swz(1 * 32 + q31, kt * 32 + hi2 * 16)), pb[kt], o1); \
      }                                                                        \
      __builtin_amdgcn_s_setprio(0);                                           \
      const float inv = 1.0f / dacc[0];                                        \
      _Pragma("unroll")                                                        \
      for (int r = 0; r < 16; ++r) {                                           \
        const int ibase = (r & 3) + 8 * (r >> 2) + 4 * hi2;                    \
        __builtin_nontemporal_store(o0[r] * inv,                               \
            &out[((size_t)b * LK + ibase) * LQ + (Q0W) + q31]);                \
        __builtin_nontemporal_store(o1[r] * inv,                               \
            &out[((size_t)b * LK + 32 + ibase) * LQ + (Q0W) + q31]);           \
      }                                                                        \
      f32x16 o2 = zero16(), o3 = zero16();                                     \
      __builtin_amdgcn_s_setprio(1);                                           \
      _Pragma("unroll")                                                        \
      for (int kt = 0; kt < 8; ++kt) {                                         \
        o2 = MFMA32(*(const bf16x8*)(sV + swz(2 * 32 + q31, kt * 32 + hi2 * 16)), pb[kt], o2); \
        o3 = MFMA32(*(const bf16x8*)(sV + swz(3 * 32 + q31, kt * 32 + hi2 * 16)), pb[kt], o3); \
      }                                                                        \
      __builtin_amdgcn_s_setprio(0);                                           \
      _Pragma("unroll")                                                        \
      for (int r = 0; r < 16; ++r) {                                           \
        const int ibase = (r & 3) + 8 * (r >> 2) + 4 * hi2;                    \
        __builtin_nontemporal_store(o2[r] * inv,                               \
            &out[((size_t)b * LK + 64 + ibase) * LQ + (Q0W) + q31]);           \
        __builtin_nontemporal_store(o3[r] * inv,                               \
            &out[((size_t)b * LK + 96 + ibase) * LQ + (Q0W) + q31]);           \
      }                                                                        \
    }                                                                          \
  }

// ---------------------------------------------------------------------------
// Main fused kernel — unchanged from r16 (bitmask mask path, XCD swizzle,
// 2-pass pipelining, NT stores). LDS 64 KB -> 2 blocks/CU.
// ---------------------------------------------------------------------------
__global__ __launch_bounds__(256, 2) void attn_kernel(
    const float* __restrict__ x1, const uint8_t* __restrict__ ws,
    float* __restrict__ out)
{
  __shared__ uint8_t sm[65536];
  uint8_t* sM = sm;            // M [128 j][128 c] bf16 swizzled
  uint8_t* sV = sm + 32768;    // V [128 i][128 j] bf16 swizzled

  const int tid = threadIdx.x, blk = blockIdx.x;
  const int xcd = blk & 7;          // hw XCD (round-robin dispatch)
  const int t   = blk >> 3;         // 0..63
  const int b   = ((t & 1) << 3) | xcd;
  const int qc  = (t >> 1) * 256;
  const int l = tid & 63, w4 = tid >> 6;
  const int q31 = l & 31, hi2 = l >> 5;

  const int q0w0 = qc + w4 * 64;        // pass-0 columns
  const int q0w1 = q0w0 + 32;           // pass-1 columns
  const size_t qrow0 = (size_t)b * LQ + q0w0 + q31;
  const size_t qrow1 = qrow0 + 32;

  const uint8_t* bm = ws + WS_BM;

  // ---- M/V image: async global->LDS (64 KB; 16 gl16 per thread) ----
  {
    const uint8_t* g = ws + WS_MV + (size_t)b * 65536;
    #pragma unroll
    for (int j = 0; j < 16; ++j)
      gl16(g + tid * 16 + j * 4096, sm + tid * 16 + j * 4096);
  }

  // ---- pass-0 x1 + bitmask loads ----
  f32x4 xr0[16];
  uintx4 mb0;
  {
    const float* xp = x1 + qrow0 * H;
    #pragma unroll
    for (int kt = 0; kt < 8; ++kt) {
      xr0[2 * kt]     = *(const f32x4*)(xp + kt * 16 + 8 * hi2);
      xr0[2 * kt + 1] = *(const f32x4*)(xp + kt * 16 + 8 * hi2 + 4);
    }
    mb0 = *(const uintx4*)(bm + qrow0 * 16);
  }
  __syncthreads();   // drains gl16 image + pass-0 loads

  bf16x8 ones1;
  #pragma unroll
  for (int e = 0; e < 8; ++e) ones1[e] = (bf16_t)1.f;

  bf16x8 pb[8];

  // ---- pass 0: S + softmax + pb ----
  CONV_S_PB(xr0, mb0)

  // ---- issue pass-1 loads (overlap with pass-0 O/store phase) ----
  f32x4 xr1[16];
  uintx4 mb1;
  {
    const float* xp = x1 + qrow1 * H;
    #pragma unroll
    for (int kt = 0; kt < 8; ++kt) {
      xr1[2 * kt]     = *(const f32x4*)(xp + kt * 16 + 8 * hi2);
      xr1[2 * kt + 1] = *(const f32x4*)(xp + kt * 16 + 8 * hi2 + 4);
    }
    mb1 = *(const uintx4*)(bm + qrow1 * 16);
  }

  // ---- pass 0: O + NT stores (pass-1 loads in flight) ----
  O_STORE(q0w0)

  // ---- pass 1 ----
  CONV_S_PB(xr1, mb1)
  O_STORE(q0w1)
}

extern "C" void kernel_launch(void* const* d_in, const int* in_sizes, int n_in,
                              void* d_out, int out_size, void* d_ws, size_t ws_size,
                              hipStream_t stream) {
  const float* x1 = (const float*)d_in[0];
  const float* x2 = (const float*)d_in[1];
  const void*  x3 = d_in[2];
  const float* wq = (const float*)d_in[3];
  const float* wk = (const float*)d_in[4];
  const float* wv = (const float*)d_in[5];
  uint8_t* ws = (uint8_t*)d_ws;
  float* out = (float*)d_out;

  prep_kernel<<<32 + 512, 512, 0, stream>>>(x2, wq, wk, wv, x3, ws);
  attn_kernel<<<NB * (LQ / 256), 256, 0, stream>>>(x1, ws, out);
}